// Round 6
// baseline (462.333 us; speedup 1.0000x reference)
//
#include <hip/hip_runtime.h>
#include <cstdint>
#include <cstddef>

// ---------------------------------------------------------------------------
// FastQuantumEvolution, dim-sliced L2-resident CSR gather.
//   dis = rsqrt(deg_col + 1)
//   prop(h)[r] = dis[r] * ( Sum_{e: row=r} h[c]*dis[c] + h[r]*dis[r] )
//   fo = prop(x); evolved = x + i*c1*fo - (c1^2/2)*prop(fo),  c1 = t*s
//   w[n] = sum_d |evolved|^2 ; w *= N / sum(w)
// D=32 split into 4 slices of 8 dims; per-slice gather operand = N*8*4B =
// 3.2 MB < 4 MB per-XCD L2. slice = blockIdx.x & 3 so each slice's blocks
// land on 2 XCDs (round-robin dispatch heuristic; perf-only).
// Output: [ w (N floats) | evolved (real-only N*32 OR interleaved N*64) ]
// ---------------------------------------------------------------------------

#define TPB 256

__device__ __forceinline__ uint32_t f2bf(float f) {
    uint32_t u = __float_as_uint(f);
    return (u + 0x7FFFu + ((u >> 16) & 1u)) >> 16;  // RNE
}
__device__ __forceinline__ uint32_t pack2(float re, float im) {
    return f2bf(re) | (f2bf(im) << 16);
}
__device__ __forceinline__ float bflo(uint32_t p) { return __uint_as_float(p << 16); }
__device__ __forceinline__ float bfhi(uint32_t p) { return __uint_as_float(p & 0xFFFF0000u); }

__global__ void k_hist(const int* __restrict__ row, const int* __restrict__ col,
                       int E, int* __restrict__ rowcnt, int* __restrict__ colcnt,
                       int* __restrict__ eoff) {
    int stride = gridDim.x * blockDim.x;
    for (int e = blockIdx.x * blockDim.x + threadIdx.x; e < E; e += stride) {
        eoff[e] = atomicAdd(&rowcnt[row[e]], 1);
        atomicAdd(&colcnt[col[e]], 1);
    }
}

__global__ void k_dis(const int* __restrict__ colcnt, float* __restrict__ dis, int N) {
    int i = blockIdx.x * blockDim.x + threadIdx.x;
    if (i < N) dis[i] = rsqrtf((float)colcnt[i] + 1.0f);  // +1 self loop
}

// xds[s][n][dd] = pack2(x*dis) for dim k = 8s+dd  (sliced, premultiplied)
__global__ void k_pack(const float* __restrict__ xr, const float* __restrict__ xi,
                       const float* __restrict__ dis, uint32_t* __restrict__ xds,
                       int N) {
    int i = blockIdx.x * blockDim.x + threadIdx.x;
    if (i < N * 32) {
        int n = i >> 5, k = i & 31, s = k >> 3, dd = k & 7;
        float dg = dis[n];
        xds[((size_t)s * N + n) * 8 + dd] = pack2(xr[i] * dg, xi[i] * dg);
    }
}

// exclusive scan, 1024 elems per 256-thread block
__global__ void k_scan1(const int* __restrict__ in, int* __restrict__ out,
                        int* __restrict__ partials, int N) {
    __shared__ int sh[256];
    int t = threadIdx.x;
    int base = blockIdx.x * 1024 + t * 4;
    int v0 = (base + 0 < N) ? in[base + 0] : 0;
    int v1 = (base + 1 < N) ? in[base + 1] : 0;
    int v2 = (base + 2 < N) ? in[base + 2] : 0;
    int v3 = (base + 3 < N) ? in[base + 3] : 0;
    int s = v0 + v1 + v2 + v3;
    sh[t] = s;
    __syncthreads();
    for (int off = 1; off < 256; off <<= 1) {
        int add = (t >= off) ? sh[t - off] : 0;
        __syncthreads();
        sh[t] += add;
        __syncthreads();
    }
    int excl = sh[t] - s;
    if (base + 0 < N) out[base + 0] = excl;
    excl += v0;
    if (base + 1 < N) out[base + 1] = excl;
    excl += v1;
    if (base + 2 < N) out[base + 2] = excl;
    excl += v2;
    if (base + 3 < N) out[base + 3] = excl;
    if (t == 255) partials[blockIdx.x] = sh[255];
}

__global__ void k_scan2(int* __restrict__ partials, int nb) {
    if (threadIdx.x == 0 && blockIdx.x == 0) {
        int acc = 0;
        for (int i = 0; i < nb; ++i) { int v = partials[i]; partials[i] = acc; acc += v; }
    }
}

__global__ void k_scan3(int* __restrict__ out, const int* __restrict__ partials,
                        int N, int E) {
    int i = blockIdx.x * blockDim.x + threadIdx.x;
    if (i < N) out[i] += partials[i >> 10];
    if (i == 0) out[N] = E;
}

__global__ void k_scatter(const int* __restrict__ row, const int* __restrict__ col,
                          const int* __restrict__ eoff, int E,
                          const int* __restrict__ rowptr, int* __restrict__ ecol) {
    int stride = gridDim.x * blockDim.x;
    for (int e = blockIdx.x * blockDim.x + threadIdx.x; e < E; e += stride)
        ecol[rowptr[row[e]] + eoff[e]] = col[e];
}

// Gather-accumulate over one node's edges from an 8-dim slice operand.
// 8-lane group per node; lane dd owns dim dd. 16 gathers in flight.
__device__ __forceinline__ void edge_accum8(const int* __restrict__ ecol,
                                            const uint32_t* __restrict__ hb,
                                            int beg, int end, int dd,
                                            float& aR, float& aI) {
    for (int base = beg; base < end; base += 16) {
        int m = end - base;
        int c0 = (dd < m)     ? ecol[base + dd]     : -1;
        int c1 = (8 + dd < m) ? ecol[base + 8 + dd] : -1;
        int cc[16];
        uint32_t p[16];
        #pragma unroll
        for (int k = 0; k < 8; ++k) {
            cc[k]     = __shfl(c0, k, 8);
            cc[k + 8] = __shfl(c1, k, 8);
        }
        #pragma unroll
        for (int k = 0; k < 16; ++k) {
            int c = cc[k] < 0 ? 0 : cc[k];
            p[k] = hb[c * 8 + dd];
        }
        #pragma unroll
        for (int k = 0; k < 16; ++k)
            if (cc[k] >= 0) { aR += bflo(p[k]); aI += bfhi(p[k]); }
    }
}

// Pass 1: fo = dis*(sum + self). Writes fo2b (bf16 fo) + fods (bf16 fo*dis).
__global__ void k_p1(const int* __restrict__ rowptr, const int* __restrict__ ecol,
                     const float* __restrict__ dis, const uint32_t* __restrict__ xds,
                     uint32_t* __restrict__ fo2b, uint32_t* __restrict__ fods, int N) {
    int s  = blockIdx.x & 3;
    int nb = blockIdx.x >> 2;
    int r  = nb * 32 + (threadIdx.x >> 3);
    int dd = threadIdx.x & 7;
    if (r >= N) return;
    const uint32_t* hb = xds + (size_t)s * N * 8;
    int beg = rowptr[r], end = rowptr[r + 1];
    float dg = dis[r];
    float aR = 0.f, aI = 0.f;
    edge_accum8(ecol, hb, beg, end, dd, aR, aI);
    uint32_t sv = hb[r * 8 + dd];  // self loop: x[r]*dis[r] (premultiplied)
    aR += bflo(sv); aI += bfhi(sv);
    float foR = dg * aR, foI = dg * aI;
    size_t o = (size_t)s * N * 8 + (size_t)r * 8 + dd;
    fo2b[o] = pack2(foR, foI);
    fods[o] = pack2(foR * dg, foI * dg);  // premultiplied for pass 2
}

// Pass 2: so = dis*(sum + self); delta = -c1*foI - c2h*soR, +c1*foR - c2h*soI.
__global__ void k_p2(const int* __restrict__ rowptr, const int* __restrict__ ecol,
                     const float* __restrict__ dis, const uint32_t* __restrict__ fo2b,
                     const uint32_t* __restrict__ fods,
                     const float* __restrict__ tptr, const float* __restrict__ dptr,
                     uint32_t* __restrict__ delta, int N) {
    int s  = blockIdx.x & 3;
    int nb = blockIdx.x >> 2;
    int r  = nb * 32 + (threadIdx.x >> 3);
    int dd = threadIdx.x & 7;
    if (r >= N) return;
    const uint32_t* hb = fods + (size_t)s * N * 8;
    int beg = rowptr[r], end = rowptr[r + 1];
    float dg = dis[r];
    float aR = 0.f, aI = 0.f;
    edge_accum8(ecol, hb, beg, end, dd, aR, aI);
    uint32_t sv = hb[r * 8 + dd];  // self loop: fo[r]*dis[r]
    aR += bflo(sv); aI += bfhi(sv);
    float soR = dg * aR, soI = dg * aI;
    size_t o = (size_t)s * N * 8 + (size_t)r * 8 + dd;
    uint32_t fp = fo2b[o];
    float foR = bflo(fp), foI = bfhi(fp);
    float c1  = tptr[0] * dptr[0];
    float c2h = 0.5f * c1 * c1;
    delta[o] = pack2(-c1 * foI - c2h * soR, c1 * foR - c2h * soI);
}

// Final: evolved = x + delta (exact f32 base), w reduce, global S.
__global__ void k_final(const float* __restrict__ xr, const float* __restrict__ xi,
                        const uint32_t* __restrict__ delta, float* __restrict__ out,
                        int N, int interleaved, float* __restrict__ S) {
    int i = blockIdx.x * blockDim.x + threadIdx.x;
    bool valid = i < N * 32;
    float er = 0.f, ei = 0.f;
    if (valid) {
        int n = i >> 5, k = i & 31, s = k >> 3, dd = k & 7;
        uint32_t dv = delta[((size_t)s * N + n) * 8 + dd];
        er = xr[i] + bflo(dv);
        ei = xi[i] + bfhi(dv);
        if (interleaved) {
            out[N + 2 * i]     = er;
            out[N + 2 * i + 1] = ei;
        } else {
            out[N + i] = er;
        }
    }
    float wv = er * er + ei * ei;
    #pragma unroll
    for (int off = 16; off; off >>= 1) wv += __shfl_xor(wv, off, 32);
    if (valid && ((threadIdx.x & 31) == 0)) out[i >> 5] = wv;  // unnormalized w
    wv += __shfl_xor(wv, 32, 64);
    __shared__ float ls[TPB / 64];
    int wave = threadIdx.x >> 6;
    if ((threadIdx.x & 63) == 0) ls[wave] = wv;
    __syncthreads();
    if (threadIdx.x == 0) {
        float bs = 0.f;
        #pragma unroll
        for (int i2 = 0; i2 < TPB / 64; ++i2) bs += ls[i2];
        atomicAdd(S, bs);
    }
}

__global__ void k_norm(float* __restrict__ w, int N, const float* __restrict__ S) {
    int i = blockIdx.x * blockDim.x + threadIdx.x;
    if (i >= N) return;
    float s = *S;
    w[i] = (s > 1e-8f) ? w[i] * ((float)N / s) : 1.0f;
}

extern "C" void kernel_launch(void* const* d_in, const int* in_sizes, int n_in,
                              void* d_out, int out_size, void* d_ws, size_t ws_size,
                              hipStream_t stream) {
    const float* xr   = (const float*)d_in[0];
    const float* xi   = (const float*)d_in[1];
    const int*   eidx = (const int*)d_in[2];
    const float* tptr = (const float*)d_in[3];
    const float* dptr = (const float*)d_in[4];

    const int N = in_sizes[0] / 32;
    const int E = in_sizes[2] / 2;
    const int* row = eidx;
    const int* col = eidx + E;
    const long long ND = (long long)N * 32;
    const int NB  = (N + 1023) / 1024;   // scan blocks
    const int NBK = (N + 31) / 32;       // node blocks for slice kernels

    // ws layout (4B units):
    // [rowcnt N | colcnt N | S 1] <- zeroed
    // [eoff E | rowptr N+1 | partials nbpad | dis N | xds ND | fo2b ND |
    //  fods ND | delta ND | ecol E]
    int*      rowcnt   = (int*)d_ws;
    int*      colcnt   = rowcnt + N;
    float*    S        = (float*)(colcnt + N);
    int*      eoff     = (int*)(S + 1);
    int*      rowptr   = eoff + E;
    int       nbpad    = (NB + 4) & ~1;
    int*      partials = rowptr + (N + 1);
    float*    dis      = (float*)(partials + nbpad);
    uint32_t* xds      = (uint32_t*)(dis + N);
    uint32_t* fo2b     = xds + ND;
    uint32_t* fods     = fo2b + ND;
    uint32_t* delta    = fods + ND;
    int*      ecol     = (int*)(delta + ND);

    hipMemsetAsync(d_ws, 0, (size_t)(2 * N + 1) * sizeof(int), stream);

    int interleaved = (out_size >= (int)(N + 2 * ND)) ? 1 : 0;
    float* out = (float*)d_out;

    k_hist<<<2048, TPB, 0, stream>>>(row, col, E, rowcnt, colcnt, eoff);
    k_dis<<<(N + TPB - 1) / TPB, TPB, 0, stream>>>(colcnt, dis, N);
    k_pack<<<(int)((ND + TPB - 1) / TPB), TPB, 0, stream>>>(xr, xi, dis, xds, N);
    k_scan1<<<NB, TPB, 0, stream>>>(rowcnt, rowptr, partials, N);
    k_scan2<<<1, 64, 0, stream>>>(partials, NB);
    k_scan3<<<(N + TPB - 1) / TPB, TPB, 0, stream>>>(rowptr, partials, N, E);
    k_scatter<<<2048, TPB, 0, stream>>>(row, col, eoff, E, rowptr, ecol);

    int pgrid = 4 * NBK;  // slice = blockIdx.x & 3 (2 XCDs per slice)
    k_p1<<<pgrid, TPB, 0, stream>>>(rowptr, ecol, dis, xds, fo2b, fods, N);
    k_p2<<<pgrid, TPB, 0, stream>>>(rowptr, ecol, dis, fo2b, fods, tptr, dptr,
                                    delta, N);
    k_final<<<(int)((ND + TPB - 1) / TPB), TPB, 0, stream>>>(xr, xi, delta, out,
                                                             N, interleaved, S);
    k_norm<<<(N + TPB - 1) / TPB, TPB, 0, stream>>>(out, N, S);
}

// Round 7
// 308.456 us; speedup vs baseline: 1.4989x; 1.4989x over previous
//
#include <hip/hip_runtime.h>
#include <cstdint>
#include <cstddef>

// ---------------------------------------------------------------------------
// FastQuantumEvolution, dim-sliced L2-resident CSR gather.
//   dis = rsqrt(deg_col + 1)
//   prop(h)[r] = dis[r] * ( Sum_{e: row=r} h[c]*dis[c] + h[r]*dis[r] )
//   fo = prop(x); evolved = x + i*c1*fo - (c1^2/2)*prop(fo),  c1 = t*s
//   w[n] = sum_d |evolved|^2 ; w *= N / sum(w)
// D=32 split into 4 slices of 8 dims; per-slice gather operand = 3.2 MB < 4 MB
// per-XCD L2. Global |psi|^2 sum via per-block partials + one reduce kernel —
// NO single-address device atomics (12.5K same-address atomicAdds were a
// ~163 us serial floor in R3-R6).
// Output: [ w (N floats) | evolved (real-only N*32 OR interleaved N*64) ]
// ---------------------------------------------------------------------------

#define TPB 256

__device__ __forceinline__ uint32_t f2bf(float f) {
    uint32_t u = __float_as_uint(f);
    return (u + 0x7FFFu + ((u >> 16) & 1u)) >> 16;  // RNE
}
__device__ __forceinline__ uint32_t pack2(float re, float im) {
    return f2bf(re) | (f2bf(im) << 16);
}
__device__ __forceinline__ float bflo(uint32_t p) { return __uint_as_float(p << 16); }
__device__ __forceinline__ float bfhi(uint32_t p) { return __uint_as_float(p & 0xFFFF0000u); }

__global__ void k_hist(const int* __restrict__ row, const int* __restrict__ col,
                       int E, int* __restrict__ rowcnt, int* __restrict__ colcnt,
                       int* __restrict__ eoff) {
    int stride = gridDim.x * blockDim.x;
    for (int e = blockIdx.x * blockDim.x + threadIdx.x; e < E; e += stride) {
        eoff[e] = atomicAdd(&rowcnt[row[e]], 1);
        atomicAdd(&colcnt[col[e]], 1);
    }
}

__global__ void k_dis(const int* __restrict__ colcnt, float* __restrict__ dis, int N) {
    int i = blockIdx.x * blockDim.x + threadIdx.x;
    if (i < N) dis[i] = rsqrtf((float)colcnt[i] + 1.0f);  // +1 self loop
}

// xds[s][n][dd] = pack2(x*dis) for dim k = 8s+dd  (sliced, premultiplied)
__global__ void k_pack(const float* __restrict__ xr, const float* __restrict__ xi,
                       const float* __restrict__ dis, uint32_t* __restrict__ xds,
                       int N) {
    int i = blockIdx.x * blockDim.x + threadIdx.x;
    if (i < N * 32) {
        int n = i >> 5, k = i & 31, s = k >> 3, dd = k & 7;
        float dg = dis[n];
        xds[((size_t)s * N + n) * 8 + dd] = pack2(xr[i] * dg, xi[i] * dg);
    }
}

// exclusive scan, 1024 elems per 256-thread block
__global__ void k_scan1(const int* __restrict__ in, int* __restrict__ out,
                        int* __restrict__ partials, int N) {
    __shared__ int sh[256];
    int t = threadIdx.x;
    int base = blockIdx.x * 1024 + t * 4;
    int v0 = (base + 0 < N) ? in[base + 0] : 0;
    int v1 = (base + 1 < N) ? in[base + 1] : 0;
    int v2 = (base + 2 < N) ? in[base + 2] : 0;
    int v3 = (base + 3 < N) ? in[base + 3] : 0;
    int s = v0 + v1 + v2 + v3;
    sh[t] = s;
    __syncthreads();
    for (int off = 1; off < 256; off <<= 1) {
        int add = (t >= off) ? sh[t - off] : 0;
        __syncthreads();
        sh[t] += add;
        __syncthreads();
    }
    int excl = sh[t] - s;
    if (base + 0 < N) out[base + 0] = excl;
    excl += v0;
    if (base + 1 < N) out[base + 1] = excl;
    excl += v1;
    if (base + 2 < N) out[base + 2] = excl;
    excl += v2;
    if (base + 3 < N) out[base + 3] = excl;
    if (t == 255) partials[blockIdx.x] = sh[255];
}

__global__ void k_scan2(int* __restrict__ partials, int nb) {
    if (threadIdx.x == 0 && blockIdx.x == 0) {
        int acc = 0;
        for (int i = 0; i < nb; ++i) { int v = partials[i]; partials[i] = acc; acc += v; }
    }
}

__global__ void k_scan3(int* __restrict__ out, const int* __restrict__ partials,
                        int N, int E) {
    int i = blockIdx.x * blockDim.x + threadIdx.x;
    if (i < N) out[i] += partials[i >> 10];
    if (i == 0) out[N] = E;
}

__global__ void k_scatter(const int* __restrict__ row, const int* __restrict__ col,
                          const int* __restrict__ eoff, int E,
                          const int* __restrict__ rowptr, int* __restrict__ ecol) {
    int stride = gridDim.x * blockDim.x;
    for (int e = blockIdx.x * blockDim.x + threadIdx.x; e < E; e += stride)
        ecol[rowptr[row[e]] + eoff[e]] = col[e];
}

// Gather-accumulate over one node's edges from an 8-dim slice operand.
// 8-lane group per node; lane dd owns dim dd. 16 gathers in flight.
__device__ __forceinline__ void edge_accum8(const int* __restrict__ ecol,
                                            const uint32_t* __restrict__ hb,
                                            int beg, int end, int dd,
                                            float& aR, float& aI) {
    for (int base = beg; base < end; base += 16) {
        int m = end - base;
        int c0 = (dd < m)     ? ecol[base + dd]     : -1;
        int c1 = (8 + dd < m) ? ecol[base + 8 + dd] : -1;
        int cc[16];
        uint32_t p[16];
        #pragma unroll
        for (int k = 0; k < 8; ++k) {
            cc[k]     = __shfl(c0, k, 8);
            cc[k + 8] = __shfl(c1, k, 8);
        }
        #pragma unroll
        for (int k = 0; k < 16; ++k) {
            int c = cc[k] < 0 ? 0 : cc[k];
            p[k] = hb[c * 8 + dd];
        }
        #pragma unroll
        for (int k = 0; k < 16; ++k)
            if (cc[k] >= 0) { aR += bflo(p[k]); aI += bfhi(p[k]); }
    }
}

// Pass 1: fo = dis*(sum + self). Writes fo2b (bf16 fo) + fods (bf16 fo*dis).
__global__ void k_p1(const int* __restrict__ rowptr, const int* __restrict__ ecol,
                     const float* __restrict__ dis, const uint32_t* __restrict__ xds,
                     uint32_t* __restrict__ fo2b, uint32_t* __restrict__ fods, int N) {
    int s  = blockIdx.x & 3;
    int nb = blockIdx.x >> 2;
    int r  = nb * 32 + (threadIdx.x >> 3);
    int dd = threadIdx.x & 7;
    if (r >= N) return;
    const uint32_t* hb = xds + (size_t)s * N * 8;
    int beg = rowptr[r], end = rowptr[r + 1];
    float dg = dis[r];
    float aR = 0.f, aI = 0.f;
    edge_accum8(ecol, hb, beg, end, dd, aR, aI);
    uint32_t sv = hb[r * 8 + dd];  // self loop: x[r]*dis[r] (premultiplied)
    aR += bflo(sv); aI += bfhi(sv);
    float foR = dg * aR, foI = dg * aI;
    size_t o = (size_t)s * N * 8 + (size_t)r * 8 + dd;
    fo2b[o] = pack2(foR, foI);
    fods[o] = pack2(foR * dg, foI * dg);  // premultiplied for pass 2
}

// Pass 2: so = dis*(sum + self); delta = (-c1*foI - c2h*soR, c1*foR - c2h*soI).
__global__ void k_p2(const int* __restrict__ rowptr, const int* __restrict__ ecol,
                     const float* __restrict__ dis, const uint32_t* __restrict__ fo2b,
                     const uint32_t* __restrict__ fods,
                     const float* __restrict__ tptr, const float* __restrict__ dptr,
                     uint32_t* __restrict__ delta, int N) {
    int s  = blockIdx.x & 3;
    int nb = blockIdx.x >> 2;
    int r  = nb * 32 + (threadIdx.x >> 3);
    int dd = threadIdx.x & 7;
    if (r >= N) return;
    const uint32_t* hb = fods + (size_t)s * N * 8;
    int beg = rowptr[r], end = rowptr[r + 1];
    float dg = dis[r];
    float aR = 0.f, aI = 0.f;
    edge_accum8(ecol, hb, beg, end, dd, aR, aI);
    uint32_t sv = hb[r * 8 + dd];  // self loop: fo[r]*dis[r]
    aR += bflo(sv); aI += bfhi(sv);
    float soR = dg * aR, soI = dg * aI;
    size_t o = (size_t)s * N * 8 + (size_t)r * 8 + dd;
    uint32_t fp = fo2b[o];
    float foR = bflo(fp), foI = bfhi(fp);
    float c1  = tptr[0] * dptr[0];
    float c2h = 0.5f * c1 * c1;
    delta[o] = pack2(-c1 * foI - c2h * soR, c1 * foR - c2h * soI);
}

// Final: evolved = x + delta (exact f32 base), per-node w, per-BLOCK partial
// (plain store — no global atomics). One thread = (node n, slice s) = 8 dims.
__global__ void k_final(const float* __restrict__ xr, const float* __restrict__ xi,
                        const uint32_t* __restrict__ delta, float* __restrict__ out,
                        int N, int interleaved, float* __restrict__ partials2) {
    int t = blockIdx.x * blockDim.x + threadIdx.x;
    int n = t >> 2, s = t & 3;
    float wsum = 0.f;
    if (n < N) {
        const uint4* dp = (const uint4*)(delta + ((size_t)s * N + n) * 8);
        uint4 d0 = dp[0], d1 = dp[1];
        size_t ib = (size_t)n * 32 + (size_t)s * 8;
        const float4* xr4 = (const float4*)(xr + ib);
        const float4* xi4 = (const float4*)(xi + ib);
        float4 a0 = xr4[0], a1 = xr4[1];
        float4 b0 = xi4[0], b1 = xi4[1];
        uint32_t dv[8] = {d0.x, d0.y, d0.z, d0.w, d1.x, d1.y, d1.z, d1.w};
        float ar[8] = {a0.x, a0.y, a0.z, a0.w, a1.x, a1.y, a1.z, a1.w};
        float ai[8] = {b0.x, b0.y, b0.z, b0.w, b1.x, b1.y, b1.z, b1.w};
        float er[8], ei[8];
        #pragma unroll
        for (int k = 0; k < 8; ++k) {
            er[k] = ar[k] + bflo(dv[k]);
            ei[k] = ai[k] + bfhi(dv[k]);
            wsum += er[k] * er[k] + ei[k] * ei[k];
        }
        if (interleaved) {
            float4* op = (float4*)(out + N + 2 * ib);
            op[0] = make_float4(er[0], ei[0], er[1], ei[1]);
            op[1] = make_float4(er[2], ei[2], er[3], ei[3]);
            op[2] = make_float4(er[4], ei[4], er[5], ei[5]);
            op[3] = make_float4(er[6], ei[6], er[7], ei[7]);
        } else {
            float4* op = (float4*)(out + N + ib);
            op[0] = make_float4(er[0], er[1], er[2], er[3]);
            op[1] = make_float4(er[4], er[5], er[6], er[7]);
        }
    }
    // per-node w: sum over the 4 slice-threads
    float nodesum = wsum;
    nodesum += __shfl_xor(nodesum, 1, 4);
    nodesum += __shfl_xor(nodesum, 2, 4);
    if (n < N && s == 0) out[n] = nodesum;  // unnormalized w
    // block partial (wave reduce + LDS)
    float bv = wsum;
    #pragma unroll
    for (int off = 32; off; off >>= 1) bv += __shfl_xor(bv, off, 64);
    __shared__ float ls[TPB / 64];
    if ((threadIdx.x & 63) == 0) ls[threadIdx.x >> 6] = bv;
    __syncthreads();
    if (threadIdx.x == 0) {
        float bs = 0.f;
        #pragma unroll
        for (int i = 0; i < TPB / 64; ++i) bs += ls[i];
        partials2[blockIdx.x] = bs;
    }
}

// Single-block reduce of per-block partials -> S.
__global__ void k_sum(const float* __restrict__ partials2, int nb,
                      float* __restrict__ S) {
    float acc = 0.f;
    for (int i = threadIdx.x; i < nb; i += blockDim.x) acc += partials2[i];
    #pragma unroll
    for (int off = 32; off; off >>= 1) acc += __shfl_xor(acc, off, 64);
    __shared__ float ls[TPB / 64];
    if ((threadIdx.x & 63) == 0) ls[threadIdx.x >> 6] = acc;
    __syncthreads();
    if (threadIdx.x == 0) {
        float s = 0.f;
        #pragma unroll
        for (int i = 0; i < TPB / 64; ++i) s += ls[i];
        *S = s;
    }
}

__global__ void k_norm(float* __restrict__ w, int N, const float* __restrict__ S) {
    int i = blockIdx.x * blockDim.x + threadIdx.x;
    if (i >= N) return;
    float s = *S;
    w[i] = (s > 1e-8f) ? w[i] * ((float)N / s) : 1.0f;
}

extern "C" void kernel_launch(void* const* d_in, const int* in_sizes, int n_in,
                              void* d_out, int out_size, void* d_ws, size_t ws_size,
                              hipStream_t stream) {
    const float* xr   = (const float*)d_in[0];
    const float* xi   = (const float*)d_in[1];
    const int*   eidx = (const int*)d_in[2];
    const float* tptr = (const float*)d_in[3];
    const float* dptr = (const float*)d_in[4];

    const int N = in_sizes[0] / 32;
    const int E = in_sizes[2] / 2;
    const int* row = eidx;
    const int* col = eidx + E;
    const long long ND = (long long)N * 32;
    const int NB  = (N + 1023) / 1024;   // scan blocks
    const int NBK = (N + 31) / 32;       // node blocks for slice kernels
    const int NFB = (int)((ND / 8 + TPB - 1) / TPB);  // k_final blocks

    // ws layout (4B units):
    // [rowcnt N | colcnt N | S 1] <- zeroed
    // [eoff E | rowptr N+1 | partials nbpad | dis N | xds ND | fo2b ND |
    //  fods ND | delta ND | ecol E | partials2 NFB]
    int*      rowcnt    = (int*)d_ws;
    int*      colcnt    = rowcnt + N;
    float*    S         = (float*)(colcnt + N);
    int*      eoff      = (int*)(S + 1);
    int*      rowptr    = eoff + E;
    int       nbpad     = (NB + 4) & ~1;
    int*      partials  = rowptr + (N + 1);
    float*    dis       = (float*)(partials + nbpad);
    uint32_t* xds       = (uint32_t*)(dis + N);
    uint32_t* fo2b      = xds + ND;
    uint32_t* fods      = fo2b + ND;
    uint32_t* delta     = fods + ND;
    int*      ecol      = (int*)(delta + ND);
    float*    partials2 = (float*)(ecol + E);

    hipMemsetAsync(d_ws, 0, (size_t)(2 * N + 1) * sizeof(int), stream);

    int interleaved = (out_size >= (int)(N + 2 * ND)) ? 1 : 0;
    float* out = (float*)d_out;

    k_hist<<<2048, TPB, 0, stream>>>(row, col, E, rowcnt, colcnt, eoff);
    k_dis<<<(N + TPB - 1) / TPB, TPB, 0, stream>>>(colcnt, dis, N);
    k_pack<<<(int)((ND + TPB - 1) / TPB), TPB, 0, stream>>>(xr, xi, dis, xds, N);
    k_scan1<<<NB, TPB, 0, stream>>>(rowcnt, rowptr, partials, N);
    k_scan2<<<1, 64, 0, stream>>>(partials, NB);
    k_scan3<<<(N + TPB - 1) / TPB, TPB, 0, stream>>>(rowptr, partials, N, E);
    k_scatter<<<2048, TPB, 0, stream>>>(row, col, eoff, E, rowptr, ecol);

    int pgrid = 4 * NBK;  // slice = blockIdx.x & 3 (2 XCDs per slice)
    k_p1<<<pgrid, TPB, 0, stream>>>(rowptr, ecol, dis, xds, fo2b, fods, N);
    k_p2<<<pgrid, TPB, 0, stream>>>(rowptr, ecol, dis, fo2b, fods, tptr, dptr,
                                    delta, N);
    k_final<<<NFB, TPB, 0, stream>>>(xr, xi, delta, out, N, interleaved, partials2);
    k_sum<<<1, TPB, 0, stream>>>(partials2, NFB, S);
    k_norm<<<(N + TPB - 1) / TPB, TPB, 0, stream>>>(out, N, S);
}